// Round 17
// baseline (8137.260 us; speedup 1.0000x reference)
//
#include <hip/hip_runtime.h>
#include <cstdint>
#include <cstddef>

typedef __bf16 bf16x8 __attribute__((ext_vector_type(8)));
typedef float f32x4v __attribute__((ext_vector_type(4)));

// ---------------- input dtype sniffing (proven) ----------------
__global__ __launch_bounds__(256) void detect_k(const uint32_t* __restrict__ hs,
                                                int* __restrict__ flag) {
  __shared__ int cnt;
  if (threadIdx.x == 0) cnt = 0;
  __syncthreads();
  uint32_t w = hs[threadIdx.x];
  int b = (w >> 8) & 0x7F;
  if (b >= 0x3C && b <= 0x40) atomicAdd(&cnt, 1);
  __syncthreads();
  if (threadIdx.x == 0) *flag = (cnt >= 128) ? 1 : 0;
}

// ---------------- dtype-adaptive converters (proven) ----------------
__global__ __launch_bounds__(256) void cvt_to_bf16_k(const void* __restrict__ src,
                                                     __bf16* __restrict__ dst, int n,
                                                     const int* __restrict__ flag) {
  int i = blockIdx.x * 256 + threadIdx.x;
  if (i >= n) return;
  float v = (*flag) ? (float)((const __bf16*)src)[i] : ((const float*)src)[i];
  dst[i] = (__bf16)v;
}

__global__ __launch_bounds__(256) void cvt_to_f32_k(const void* __restrict__ src,
                                                    float* __restrict__ dst, int n,
                                                    const int* __restrict__ flag) {
  int i = blockIdx.x * 256 + threadIdx.x;
  if (i >= n) return;
  dst[i] = (*flag) ? (float)((const __bf16*)src)[i] : ((const float*)src)[i];
}

// ---------------- sgemm64 v2 (R16-proven): vectorized staging, z-fused ----------
__global__ __launch_bounds__(256) void sgemm64_k(const __bf16* __restrict__ A,
                                                 const __bf16* __restrict__ B,
                                                 const float* __restrict__ bias,
                                                 __bf16* __restrict__ C,
                                                 int M, int N, int K, int ldc, int coloff) {
  __shared__ float As[16][65];
  __shared__ float Bs[16][65];
  const int tx = threadIdx.x, ty = threadIdx.y;
  const int tid = ty * 16 + tx;
  const int z = blockIdx.z;
  const __bf16* Bz = B + (size_t)z * 1048576;
  const float* biasz = bias + z * 1024;
  const int coloffz = coloff + z * 1024;
  const int m0 = blockIdx.x * 64, n0 = blockIdx.y * 64;
  float acc[4][4] = {};
  for (int kt = 0; kt < K; kt += 16) {
    if (tid < 128) {
      int ml = tid >> 1, half = tid & 1;
      bf16x8 av = *(const bf16x8*)(A + (size_t)(m0 + ml) * K + kt + half * 8);
#pragma unroll
      for (int j = 0; j < 8; ++j) As[half * 8 + j][ml] = (float)av[j];
    } else {
      int t2 = tid - 128;
      int kk = t2 >> 3, seg = t2 & 7;
      bf16x8 bv = *(const bf16x8*)(Bz + (size_t)(kt + kk) * N + n0 + seg * 8);
#pragma unroll
      for (int j = 0; j < 8; ++j) Bs[kk][seg * 8 + j] = (float)bv[j];
    }
    __syncthreads();
#pragma unroll
    for (int kk = 0; kk < 16; ++kk) {
      float a[4], b[4];
#pragma unroll
      for (int i = 0; i < 4; ++i) a[i] = As[kk][ty * 4 + i];
#pragma unroll
      for (int i = 0; i < 4; ++i) b[i] = Bs[kk][tx * 4 + i];
#pragma unroll
      for (int i = 0; i < 4; ++i)
#pragma unroll
        for (int j = 0; j < 4; ++j) acc[i][j] += a[i] * b[j];
    }
    __syncthreads();
  }
#pragma unroll
  for (int i = 0; i < 4; ++i) {
    int row = m0 + ty * 4 + i;
#pragma unroll
    for (int j = 0; j < 4; ++j) {
      int col = n0 + tx * 4 + j;
      C[(size_t)row * ldc + coloffz + col] = (__bf16)(acc[i][j] + biasz[col]);
    }
  }
}

__global__ __launch_bounds__(256) void sgemm64_out_k(const __bf16* __restrict__ A,
                                                     const __bf16* __restrict__ B,
                                                     const float* __restrict__ bias,
                                                     void* __restrict__ out,
                                                     int M, int N, int K,
                                                     const int* __restrict__ flag) {
  __shared__ float As[16][65];
  __shared__ float Bs[16][65];
  const int tx = threadIdx.x, ty = threadIdx.y;
  const int tid = ty * 16 + tx;
  const int m0 = blockIdx.x * 64, n0 = blockIdx.y * 64;
  float acc[4][4] = {};
  for (int kt = 0; kt < K; kt += 16) {
    if (tid < 128) {
      int ml = tid >> 1, half = tid & 1;
      bf16x8 av = *(const bf16x8*)(A + (size_t)(m0 + ml) * K + kt + half * 8);
#pragma unroll
      for (int j = 0; j < 8; ++j) As[half * 8 + j][ml] = (float)av[j];
    } else {
      int t2 = tid - 128;
      int kk = t2 >> 3, seg = t2 & 7;
      bf16x8 bv = *(const bf16x8*)(B + (size_t)(kt + kk) * N + n0 + seg * 8);
#pragma unroll
      for (int j = 0; j < 8; ++j) Bs[kk][seg * 8 + j] = (float)bv[j];
    }
    __syncthreads();
#pragma unroll
    for (int kk = 0; kk < 16; ++kk) {
      float a[4], b[4];
#pragma unroll
      for (int i = 0; i < 4; ++i) a[i] = As[kk][ty * 4 + i];
#pragma unroll
      for (int i = 0; i < 4; ++i) b[i] = Bs[kk][tx * 4 + i];
#pragma unroll
      for (int i = 0; i < 4; ++i)
#pragma unroll
        for (int j = 0; j < 4; ++j) acc[i][j] += a[i] * b[j];
    }
    __syncthreads();
  }
  int use16 = *flag;
#pragma unroll
  for (int i = 0; i < 4; ++i) {
    int row = m0 + ty * 4 + i;
#pragma unroll
    for (int j = 0; j < 4; ++j) {
      int col = n0 + tx * 4 + j;
      float r = acc[i][j] + bias[col];
      size_t idx = (size_t)row * N + col;
      if (use16) ((__bf16*)out)[idx] = (__bf16)r;
      else       ((float*)out)[idx] = r;
    }
  }
}

// ---------------- V transpose (proven) ----------------
__global__ __launch_bounds__(256) void vt_k(const __bf16* __restrict__ QKVb,
                                            __bf16* __restrict__ Vt) {
  __shared__ __bf16 t[64][72];
  const int h = blockIdx.x, k0 = blockIdx.y * 64;
  const int tid = threadIdx.x;
  const int r = tid >> 2, dc = (tid & 3) * 16;
  const __bf16* src = QKVb + (size_t)(k0 + r) * 3072 + 2048 + h * 64 + dc;
  *(bf16x8*)(&t[r][dc]) = *(const bf16x8*)(src);
  *(bf16x8*)(&t[r][dc + 8]) = *(const bf16x8*)(src + 8);
  __syncthreads();
  const int dr = tid >> 2, kc = (tid & 3) * 16;
  __bf16* dst = Vt + ((size_t)(h * 64 + dr)) * 1024 + k0 + kc;
  bf16x8 o0, o1;
#pragma unroll
  for (int j = 0; j < 8; ++j) { o0[j] = t[kc + j][dr]; o1[j] = t[kc + 8 + j][dr]; }
  *(bf16x8*)dst = o0;
  *(bf16x8*)(dst + 8) = o1;
}

// ---------------- attention v8: f32 Q in LDS + interleaved 4-chain score -------------
// grid (256, 16); 256 threads. Per-row accumulation order identical to v7/R4
// -> bit-identical output. K-element converted once (shared by 4 rows); 4
// independent FMA chains interleave to hide dependency latency.
__global__ __launch_bounds__(256) void attn_v8_k(const __bf16* __restrict__ QKV,
                                                 const __bf16* __restrict__ Vt,
                                                 const float* __restrict__ amask,
                                                 const __bf16* __restrict__ rel16,
                                                 const float* __restrict__ Mg,
                                                 const float* __restrict__ zg,
                                                 const float* __restrict__ ga,
                                                 __bf16* __restrict__ comb) {
  const int q0 = blockIdx.x * 4, h = blockIdx.y;
  const int tid = threadIdx.x;
  __shared__ float sc[4][1024];
  __shared__ float qsf[4][64];
  __shared__ f32x4v red4[256];
  __shared__ float ov[4][4][64];   // [wave][qq][d]
  __shared__ float sq_s[4][64];

  {
    int qq = tid >> 6, d = tid & 63;
    qsf[qq][d] = (float)QKV[(size_t)(q0 + qq) * 3072 + h * 64 + d];
  }
  __syncthreads();

  // scores: thread owns k = tid + 256*jj
#pragma unroll 1
  for (int jj = 0; jj < 4; ++jj) {
    int k = tid + jj * 256;
    const __bf16* kp = QKV + (size_t)k * 3072 + 1024 + h * 64;
    bf16x8 kv[8];
#pragma unroll
    for (int c = 0; c < 8; ++c) kv[c] = *(const bf16x8*)(kp + c * 8);
    float mk = amask[k] * (-1e9f);
    const __bf16* rbase = rel16 + (size_t)(q0 - k + 1024) * 64;
    float s0 = 0.f, s1 = 0.f, s2 = 0.f, s3 = 0.f;
#pragma unroll 1
    for (int c = 0; c < 8; ++c) {
      bf16x8 kvv = kv[c];
      bf16x8 r0 = *(const bf16x8*)(rbase + c * 8);
      bf16x8 r1 = *(const bf16x8*)(rbase + 64 + c * 8);
      bf16x8 r2 = *(const bf16x8*)(rbase + 128 + c * 8);
      bf16x8 r3 = *(const bf16x8*)(rbase + 192 + c * 8);
      const float* q0p = &qsf[0][c * 8];
      const float* q1p = &qsf[1][c * 8];
      const float* q2p = &qsf[2][c * 8];
      const float* q3p = &qsf[3][c * 8];
#pragma unroll
      for (int e = 0; e < 8; ++e) {
        float kf = (float)kvv[e];
        s0 += (q0p[e] + (float)r0[e]) * kf;
        s1 += (q1p[e] + (float)r1[e]) * kf;
        s2 += (q2p[e] + (float)r2[e]) * kf;
        s3 += (q3p[e] + (float)r3[e]) * kf;
      }
    }
    sc[0][k] = s0 * 0.125f + mk;
    sc[1][k] = s1 * 0.125f + mk;
    sc[2][k] = s2 * 0.125f + mk;
    sc[3][k] = s3 * 0.125f + mk;
  }
  __syncthreads();

  // 4-row max reduce
  f32x4v mx;
  mx[0] = mx[1] = mx[2] = mx[3] = -3.0e38f;
  for (int k = tid; k < 1024; k += 256) {
    mx[0] = fmaxf(mx[0], sc[0][k]);
    mx[1] = fmaxf(mx[1], sc[1][k]);
    mx[2] = fmaxf(mx[2], sc[2][k]);
    mx[3] = fmaxf(mx[3], sc[3][k]);
  }
  red4[tid] = mx;
  __syncthreads();
  for (int s = 128; s > 0; s >>= 1) {
    if (tid < s) {
      f32x4v a = red4[tid], b = red4[tid + s];
      a[0] = fmaxf(a[0], b[0]); a[1] = fmaxf(a[1], b[1]);
      a[2] = fmaxf(a[2], b[2]); a[3] = fmaxf(a[3], b[3]);
      red4[tid] = a;
    }
    __syncthreads();
  }
  f32x4v mrow = red4[0];
  __syncthreads();

  // exp + 4-row sum
  f32x4v lp = {0.f, 0.f, 0.f, 0.f};
  for (int k = tid; k < 1024; k += 256) {
    float e0 = __expf(sc[0][k] - mrow[0]); sc[0][k] = e0; lp[0] += e0;
    float e1 = __expf(sc[1][k] - mrow[1]); sc[1][k] = e1; lp[1] += e1;
    float e2 = __expf(sc[2][k] - mrow[2]); sc[2][k] = e2; lp[2] += e2;
    float e3 = __expf(sc[3][k] - mrow[3]); sc[3][k] = e3; lp[3] += e3;
  }
  red4[tid] = lp;
  __syncthreads();
  for (int s = 128; s > 0; s >>= 1) {
    if (tid < s) {
      f32x4v a = red4[tid], b = red4[tid + s];
      a[0] += b[0]; a[1] += b[1]; a[2] += b[2]; a[3] += b[3];
      red4[tid] = a;
    }
    __syncthreads();
  }
  f32x4v lsum = red4[0];

  // PV: V chunk loaded once, reused 4x
  const int d = tid & 63, w4 = tid >> 6;
  float o0 = 0.f, o1 = 0.f, o2 = 0.f, o3 = 0.f;
  const __bf16* vrow = Vt + ((size_t)(h * 64 + d)) * 1024 + w4 * 256;
#pragma unroll 4
  for (int c = 0; c < 32; ++c) {
    bf16x8 vv = *(const bf16x8*)(vrow + c * 8);
    int k0 = w4 * 256 + c * 8;
#pragma unroll
    for (int e = 0; e < 8; ++e) {
      float v = (float)vv[e];
      o0 += sc[0][k0 + e] * v;
      o1 += sc[1][k0 + e] * v;
      o2 += sc[2][k0 + e] * v;
      o3 += sc[3][k0 + e] * v;
    }
  }
  ov[w4][0][d] = o0; ov[w4][1][d] = o1; ov[w4][2][d] = o2; ov[w4][3][d] = o3;
  __syncthreads();

  {
    int qq = tid >> 6, dd = tid & 63;
    float x = qsf[qq][dd];
    sq_s[qq][dd] = x > 0.f ? x + 1.f : __expf(x);
  }
  __syncthreads();

  // epilogue: all 256 threads (group qq = tid>>6 handles q-row qq)
  {
    int qq = tid >> 6, d2 = tid & 63;
    float local = (ov[0][qq][d2] + ov[1][qq][d2] + ov[2][qq][d2] + ov[3][qq][d2]) /
                  lsum[qq];
    float num = 0.f, den = 1e-6f;
#pragma unroll
    for (int dd = 0; dd < 64; ++dd) {
      float sqv = sq_s[qq][dd];
      num += sqv * Mg[(size_t)h * 4096 + dd * 64 + d2];
      den += sqv * zg[h * 64 + dd];
    }
    float gate = 1.f / (1.f + __expf(-ga[0]));
    float cv = gate * local + (1.f - gate) * num / den;
    comb[(size_t)(q0 + qq) * 1024 + h * 64 + d2] = (__bf16)cv;
  }
}

// ---------------- fallback attention (round-4-proven, verbatim) ----------------
__global__ __launch_bounds__(256) void attn_simple_k(const __bf16* __restrict__ QKV,
                                                     const float* __restrict__ amask,
                                                     const __bf16* __restrict__ rel16,
                                                     const float* __restrict__ Mg,
                                                     const float* __restrict__ zg,
                                                     const float* __restrict__ ga,
                                                     __bf16* __restrict__ comb) {
  const int q = blockIdx.x, h = blockIdx.y;
  const int tid = threadIdx.x;
  __shared__ float sc[1024];
  __shared__ float qs[64];
  __shared__ float red[256];
  __shared__ float ov[4][64];
  __shared__ float sq_s[64];

  if (tid < 64) qs[tid] = (float)QKV[(size_t)q * 3072 + h * 64 + tid];
  __syncthreads();

#pragma unroll
  for (int j = 0; j < 4; ++j) {
    int k = tid * 4 + j;
    const __bf16* kp = QKV + (size_t)k * 3072 + 1024 + h * 64;
    const __bf16* rp = rel16 + (size_t)(q - k + 1024) * 64;
    float s = 0.f;
#pragma unroll
    for (int c = 0; c < 8; ++c) {
      bf16x8 kv = *(const bf16x8*)(kp + c * 8);
      bf16x8 rv = *(const bf16x8*)(rp + c * 8);
#pragma unroll
      for (int e = 0; e < 8; ++e)
        s += (qs[c * 8 + e] + (float)rv[e]) * (float)kv[e];
    }
    sc[k] = s * 0.125f + amask[k] * (-1e9f);
  }
  __syncthreads();

  float m = -3.0e38f;
  for (int k = tid; k < 1024; k += 256) m = fmaxf(m, sc[k]);
  red[tid] = m;
  __syncthreads();
  for (int s = 128; s > 0; s >>= 1) {
    if (tid < s) red[tid] = fmaxf(red[tid], red[tid + s]);
    __syncthreads();
  }
  m = red[0];
  __syncthreads();

  float lp = 0.f;
  for (int k = tid; k < 1024; k += 256) {
    float e = __expf(sc[k] - m);
    sc[k] = e;
    lp += e;
  }
  red[tid] = lp;
  __syncthreads();
  for (int s = 128; s > 0; s >>= 1) {
    if (tid < s) red[tid] += red[tid + s];
    __syncthreads();
  }
  float lsum = red[0];

  const int d = tid & 63, w4 = tid >> 6;
  float o = 0.f;
  const __bf16* vbase = QKV + (size_t)(w4 * 256) * 3072 + 2048 + h * 64 + d;
  for (int k = 0; k < 256; ++k) o += sc[w4 * 256 + k] * (float)vbase[(size_t)k * 3072];
  ov[w4][d] = o;
  __syncthreads();

  if (tid < 64) {
    float x = qs[tid];
    sq_s[tid] = x > 0.f ? x + 1.f : __expf(x);
  }
  __syncthreads();
  if (tid < 64) {
    float local = (ov[0][tid] + ov[1][tid] + ov[2][tid] + ov[3][tid]) / lsum;
    float num = 0.f, den = 1e-6f;
    for (int dd = 0; dd < 64; ++dd) {
      num += sq_s[dd] * Mg[(size_t)h * 4096 + dd * 64 + tid];
      den += sq_s[dd] * zg[h * 64 + dd];
    }
    float gate = 1.f / (1.f + __expf(-ga[0]));
    float cv = gate * local + (1.f - gate) * num / den;
    comb[(size_t)q * 1024 + h * 64 + tid] = (__bf16)cv;
  }
}

// ---------------- launcher ----------------
extern "C" void kernel_launch(void* const* d_in, const int* in_sizes, int n_in,
                              void* d_out, int out_size, void* d_ws, size_t ws_size,
                              hipStream_t stream) {
  const int expect[14] = {4194304, 4096, 1048576, 1024, 1048576, 1024, 1048576,
                          1024, 1048576, 1024, 131136, 65536, 1024, 1};
  if (n_in != 14) return;
  for (int i = 0; i < 14; ++i)
    if (in_sizes[i] != expect[i]) return;

  char* ws = (char*)d_ws;
  int*    flag  = (int*)ws;                      // 4B
  float*  am32  = (float*)(ws + 1024);           // [4096]
  float*  b32   = (float*)(ws + 17408);          // bq|bk|bv|bo  [4][1024]
  float*  zg32  = (float*)(ws + 33792);          // [1024]
  float*  ga32  = (float*)(ws + 37888);          // [1]
  float*  Mg32  = (float*)(ws + 38912);          // [65536]
  __bf16* rel16 = (__bf16*)(ws + 301056);        // [131136]
  __bf16* hs16  = (__bf16*)(ws + 565248);        // [4096][1024]
  __bf16* W16   = (__bf16*)(ws + 8953856);       // 4x [1024][1024] (q,k,v,o)
  __bf16* qkv_b = (__bf16*)(ws + 17342464);      // [1024][3072]
  __bf16* comb  = (__bf16*)(ws + 23633920);      // [4096][1024]  ends 32022528
  __bf16* Vt    = (__bf16*)(ws + 32022528);      // [16][64][1024] ends 34119680

  const bool useVt = (ws_size >= 34119680);      // R12/R14/R15/R16-proven true

  detect_k<<<1, 256, 0, stream>>>((const uint32_t*)d_in[0], flag);

  cvt_to_bf16_k<<<16384, 256, 0, stream>>>(d_in[0], hs16, 4194304, flag);
  cvt_to_f32_k<<<16, 256, 0, stream>>>(d_in[1], am32, 4096, flag);
  const int widx[4] = {2, 4, 6, 8};
  for (int j = 0; j < 4; ++j) {
    cvt_to_bf16_k<<<4096, 256, 0, stream>>>(d_in[widx[j]], W16 + (size_t)j * 1048576,
                                            1048576, flag);
    cvt_to_f32_k<<<4, 256, 0, stream>>>(d_in[widx[j] + 1], b32 + j * 1024, 1024, flag);
  }
  cvt_to_bf16_k<<<513, 256, 0, stream>>>(d_in[10], rel16, 131136, flag);
  cvt_to_f32_k<<<256, 256, 0, stream>>>(d_in[11], Mg32, 65536, flag);
  cvt_to_f32_k<<<4, 256, 0, stream>>>(d_in[12], zg32, 1024, flag);
  cvt_to_f32_k<<<1, 256, 0, stream>>>(d_in[13], ga32, 1, flag);

  for (int b = 0; b < 4; ++b) {
    sgemm64_k<<<dim3(16, 16, 3), dim3(16, 16), 0, stream>>>(
        hs16 + (size_t)b * 1048576, W16, b32, qkv_b, 1024, 1024, 1024, 3072, 0);
    if (useVt) {
      vt_k<<<dim3(16, 16), 256, 0, stream>>>(qkv_b, Vt);
      attn_v8_k<<<dim3(256, 16), 256, 0, stream>>>(
          qkv_b, Vt, am32 + b * 1024, rel16, Mg32, zg32, ga32,
          comb + (size_t)b * 1048576);
    } else {
      attn_simple_k<<<dim3(1024, 16), 256, 0, stream>>>(
          qkv_b, am32 + b * 1024, rel16, Mg32, zg32, ga32, comb + (size_t)b * 1048576);
    }
  }

  sgemm64_out_k<<<dim3(64, 16), dim3(16, 16), 0, stream>>>(
      comb, W16 + 3 * 1048576, b32 + 3 * 1024, d_out, 4096, 1024, 1024, flag);
}

// Round 18
// 2360.585 us; speedup vs baseline: 3.4471x; 3.4471x over previous
//
#include <hip/hip_runtime.h>
#include <cstdint>
#include <cstddef>

typedef __bf16 bf16x8 __attribute__((ext_vector_type(8)));
typedef float f32x4v __attribute__((ext_vector_type(4)));

// ---------------- input dtype sniffing (proven) ----------------
__global__ __launch_bounds__(256) void detect_k(const uint32_t* __restrict__ hs,
                                                int* __restrict__ flag) {
  __shared__ int cnt;
  if (threadIdx.x == 0) cnt = 0;
  __syncthreads();
  uint32_t w = hs[threadIdx.x];
  int b = (w >> 8) & 0x7F;
  if (b >= 0x3C && b <= 0x40) atomicAdd(&cnt, 1);
  __syncthreads();
  if (threadIdx.x == 0) *flag = (cnt >= 128) ? 1 : 0;
}

// ---------------- dtype-adaptive converters (proven) ----------------
__global__ __launch_bounds__(256) void cvt_to_bf16_k(const void* __restrict__ src,
                                                     __bf16* __restrict__ dst, int n,
                                                     const int* __restrict__ flag) {
  int i = blockIdx.x * 256 + threadIdx.x;
  if (i >= n) return;
  float v = (*flag) ? (float)((const __bf16*)src)[i] : ((const float*)src)[i];
  dst[i] = (__bf16)v;
}

__global__ __launch_bounds__(256) void cvt_to_f32_k(const void* __restrict__ src,
                                                    float* __restrict__ dst, int n,
                                                    const int* __restrict__ flag) {
  int i = blockIdx.x * 256 + threadIdx.x;
  if (i >= n) return;
  dst[i] = (*flag) ? (float)((const __bf16*)src)[i] : ((const float*)src)[i];
}

// ---------------- sgemm64 v2 (R16-proven): vectorized staging, z-fused ----------
__global__ __launch_bounds__(256) void sgemm64_k(const __bf16* __restrict__ A,
                                                 const __bf16* __restrict__ B,
                                                 const float* __restrict__ bias,
                                                 __bf16* __restrict__ C,
                                                 int M, int N, int K, int ldc, int coloff) {
  __shared__ float As[16][65];
  __shared__ float Bs[16][65];
  const int tx = threadIdx.x, ty = threadIdx.y;
  const int tid = ty * 16 + tx;
  const int z = blockIdx.z;
  const __bf16* Bz = B + (size_t)z * 1048576;
  const float* biasz = bias + z * 1024;
  const int coloffz = coloff + z * 1024;
  const int m0 = blockIdx.x * 64, n0 = blockIdx.y * 64;
  float acc[4][4] = {};
  for (int kt = 0; kt < K; kt += 16) {
    if (tid < 128) {
      int ml = tid >> 1, half = tid & 1;
      bf16x8 av = *(const bf16x8*)(A + (size_t)(m0 + ml) * K + kt + half * 8);
#pragma unroll
      for (int j = 0; j < 8; ++j) As[half * 8 + j][ml] = (float)av[j];
    } else {
      int t2 = tid - 128;
      int kk = t2 >> 3, seg = t2 & 7;
      bf16x8 bv = *(const bf16x8*)(Bz + (size_t)(kt + kk) * N + n0 + seg * 8);
#pragma unroll
      for (int j = 0; j < 8; ++j) Bs[kk][seg * 8 + j] = (float)bv[j];
    }
    __syncthreads();
#pragma unroll
    for (int kk = 0; kk < 16; ++kk) {
      float a[4], b[4];
#pragma unroll
      for (int i = 0; i < 4; ++i) a[i] = As[kk][ty * 4 + i];
#pragma unroll
      for (int i = 0; i < 4; ++i) b[i] = Bs[kk][tx * 4 + i];
#pragma unroll
      for (int i = 0; i < 4; ++i)
#pragma unroll
        for (int j = 0; j < 4; ++j) acc[i][j] += a[i] * b[j];
    }
    __syncthreads();
  }
#pragma unroll
  for (int i = 0; i < 4; ++i) {
    int row = m0 + ty * 4 + i;
#pragma unroll
    for (int j = 0; j < 4; ++j) {
      int col = n0 + tx * 4 + j;
      C[(size_t)row * ldc + coloffz + col] = (__bf16)(acc[i][j] + biasz[col]);
    }
  }
}

__global__ __launch_bounds__(256) void sgemm64_out_k(const __bf16* __restrict__ A,
                                                     const __bf16* __restrict__ B,
                                                     const float* __restrict__ bias,
                                                     void* __restrict__ out,
                                                     int M, int N, int K,
                                                     const int* __restrict__ flag) {
  __shared__ float As[16][65];
  __shared__ float Bs[16][65];
  const int tx = threadIdx.x, ty = threadIdx.y;
  const int tid = ty * 16 + tx;
  const int m0 = blockIdx.x * 64, n0 = blockIdx.y * 64;
  float acc[4][4] = {};
  for (int kt = 0; kt < K; kt += 16) {
    if (tid < 128) {
      int ml = tid >> 1, half = tid & 1;
      bf16x8 av = *(const bf16x8*)(A + (size_t)(m0 + ml) * K + kt + half * 8);
#pragma unroll
      for (int j = 0; j < 8; ++j) As[half * 8 + j][ml] = (float)av[j];
    } else {
      int t2 = tid - 128;
      int kk = t2 >> 3, seg = t2 & 7;
      bf16x8 bv = *(const bf16x8*)(B + (size_t)(kt + kk) * N + n0 + seg * 8);
#pragma unroll
      for (int j = 0; j < 8; ++j) Bs[kk][seg * 8 + j] = (float)bv[j];
    }
    __syncthreads();
#pragma unroll
    for (int kk = 0; kk < 16; ++kk) {
      float a[4], b[4];
#pragma unroll
      for (int i = 0; i < 4; ++i) a[i] = As[kk][ty * 4 + i];
#pragma unroll
      for (int i = 0; i < 4; ++i) b[i] = Bs[kk][tx * 4 + i];
#pragma unroll
      for (int i = 0; i < 4; ++i)
#pragma unroll
        for (int j = 0; j < 4; ++j) acc[i][j] += a[i] * b[j];
    }
    __syncthreads();
  }
  int use16 = *flag;
#pragma unroll
  for (int i = 0; i < 4; ++i) {
    int row = m0 + ty * 4 + i;
#pragma unroll
    for (int j = 0; j < 4; ++j) {
      int col = n0 + tx * 4 + j;
      float r = acc[i][j] + bias[col];
      size_t idx = (size_t)row * N + col;
      if (use16) ((__bf16*)out)[idx] = (__bf16)r;
      else       ((float*)out)[idx] = r;
    }
  }
}

// ---------------- V transpose (proven) ----------------
__global__ __launch_bounds__(256) void vt_k(const __bf16* __restrict__ QKVb,
                                            __bf16* __restrict__ Vt) {
  __shared__ __bf16 t[64][72];
  const int h = blockIdx.x, k0 = blockIdx.y * 64;
  const int tid = threadIdx.x;
  const int r = tid >> 2, dc = (tid & 3) * 16;
  const __bf16* src = QKVb + (size_t)(k0 + r) * 3072 + 2048 + h * 64 + dc;
  *(bf16x8*)(&t[r][dc]) = *(const bf16x8*)(src);
  *(bf16x8*)(&t[r][dc + 8]) = *(const bf16x8*)(src + 8);
  __syncthreads();
  const int dr = tid >> 2, kc = (tid & 3) * 16;
  __bf16* dst = Vt + ((size_t)(h * 64 + dr)) * 1024 + k0 + kc;
  bf16x8 o0, o1;
#pragma unroll
  for (int j = 0; j < 8; ++j) { o0[j] = t[kc + j][dr]; o1[j] = t[kc + 8 + j][dr]; }
  *(bf16x8*)dst = o0;
  *(bf16x8*)(dst + 8) = o1;
}

// ---------------- attention v9: v7 + 4-way partial accumulators (single delta) -------
// grid (256, 16); 256 threads. Memory access pattern BYTE-IDENTICAL to v7
// (R16-proven). Only change: score dot uses 4 independent partial sums
// (p[c&3], compile-time index) tree-summed at the end -> 4x shorter FMA
// dependency chains. fp32 reassociation only; threshold headroom ~4x.
__global__ __launch_bounds__(256) void attn_v9_k(const __bf16* __restrict__ QKV,
                                                 const __bf16* __restrict__ Vt,
                                                 const float* __restrict__ amask,
                                                 const __bf16* __restrict__ rel16,
                                                 const float* __restrict__ Mg,
                                                 const float* __restrict__ zg,
                                                 const float* __restrict__ ga,
                                                 __bf16* __restrict__ comb) {
  const int q0 = blockIdx.x * 4, h = blockIdx.y;
  const int tid = threadIdx.x;
  __shared__ float sc[4][1024];
  __shared__ __bf16 qsb[4][64];
  __shared__ f32x4v red4[256];
  __shared__ float ov[4][4][64];   // [wave][qq][d]
  __shared__ float sq_s[4][64];

  {
    int qq = tid >> 6, d = tid & 63;
    qsb[qq][d] = QKV[(size_t)(q0 + qq) * 3072 + h * 64 + d];
  }
  __syncthreads();

  // scores: thread owns k = tid + 256*jj; K row in regs, qq sequential
#pragma unroll 1
  for (int jj = 0; jj < 4; ++jj) {
    int k = tid + jj * 256;
    const __bf16* kp = QKV + (size_t)k * 3072 + 1024 + h * 64;
    bf16x8 kv[8];
#pragma unroll
    for (int c = 0; c < 8; ++c) kv[c] = *(const bf16x8*)(kp + c * 8);
    float mk = amask[k] * (-1e9f);
#pragma unroll 1
    for (int qq = 0; qq < 4; ++qq) {
      const __bf16* rp = rel16 + (size_t)(q0 + qq - k + 1024) * 64;
      const __bf16* qp = &qsb[qq][0];
      float p[4] = {0.f, 0.f, 0.f, 0.f};
#pragma unroll
      for (int c = 0; c < 8; ++c) {
        bf16x8 rv = *(const bf16x8*)(rp + c * 8);
        bf16x8 qv = *(const bf16x8*)(qp + c * 8);
#pragma unroll
        for (int e = 0; e < 8; ++e)
          p[c & 3] += ((float)qv[e] + (float)rv[e]) * (float)kv[c][e];
      }
      float s = (p[0] + p[1]) + (p[2] + p[3]);
      sc[qq][k] = s * 0.125f + mk;
    }
  }
  __syncthreads();

  // 4-row max reduce
  f32x4v mx;
  mx[0] = mx[1] = mx[2] = mx[3] = -3.0e38f;
  for (int k = tid; k < 1024; k += 256) {
    mx[0] = fmaxf(mx[0], sc[0][k]);
    mx[1] = fmaxf(mx[1], sc[1][k]);
    mx[2] = fmaxf(mx[2], sc[2][k]);
    mx[3] = fmaxf(mx[3], sc[3][k]);
  }
  red4[tid] = mx;
  __syncthreads();
  for (int s = 128; s > 0; s >>= 1) {
    if (tid < s) {
      f32x4v a = red4[tid], b = red4[tid + s];
      a[0] = fmaxf(a[0], b[0]); a[1] = fmaxf(a[1], b[1]);
      a[2] = fmaxf(a[2], b[2]); a[3] = fmaxf(a[3], b[3]);
      red4[tid] = a;
    }
    __syncthreads();
  }
  f32x4v mrow = red4[0];
  __syncthreads();

  // exp + 4-row sum
  f32x4v lp = {0.f, 0.f, 0.f, 0.f};
  for (int k = tid; k < 1024; k += 256) {
    float e0 = __expf(sc[0][k] - mrow[0]); sc[0][k] = e0; lp[0] += e0;
    float e1 = __expf(sc[1][k] - mrow[1]); sc[1][k] = e1; lp[1] += e1;
    float e2 = __expf(sc[2][k] - mrow[2]); sc[2][k] = e2; lp[2] += e2;
    float e3 = __expf(sc[3][k] - mrow[3]); sc[3][k] = e3; lp[3] += e3;
  }
  red4[tid] = lp;
  __syncthreads();
  for (int s = 128; s > 0; s >>= 1) {
    if (tid < s) {
      f32x4v a = red4[tid], b = red4[tid + s];
      a[0] += b[0]; a[1] += b[1]; a[2] += b[2]; a[3] += b[3];
      red4[tid] = a;
    }
    __syncthreads();
  }
  f32x4v lsum = red4[0];

  // PV: V chunk loaded once, reused 4x (4 interleaved chains, unchanged)
  const int d = tid & 63, w4 = tid >> 6;
  float o0 = 0.f, o1 = 0.f, o2 = 0.f, o3 = 0.f;
  const __bf16* vrow = Vt + ((size_t)(h * 64 + d)) * 1024 + w4 * 256;
#pragma unroll 4
  for (int c = 0; c < 32; ++c) {
    bf16x8 vv = *(const bf16x8*)(vrow + c * 8);
    int k0 = w4 * 256 + c * 8;
#pragma unroll
    for (int e = 0; e < 8; ++e) {
      float v = (float)vv[e];
      o0 += sc[0][k0 + e] * v;
      o1 += sc[1][k0 + e] * v;
      o2 += sc[2][k0 + e] * v;
      o3 += sc[3][k0 + e] * v;
    }
  }
  ov[w4][0][d] = o0; ov[w4][1][d] = o1; ov[w4][2][d] = o2; ov[w4][3][d] = o3;
  __syncthreads();

  {
    int qq = tid >> 6, dd = tid & 63;
    float x = (float)qsb[qq][dd];
    sq_s[qq][dd] = x > 0.f ? x + 1.f : __expf(x);
  }
  __syncthreads();

  // epilogue: all 256 threads (group qq = tid>>6 handles q-row qq)
  {
    int qq = tid >> 6, d2 = tid & 63;
    float local = (ov[0][qq][d2] + ov[1][qq][d2] + ov[2][qq][d2] + ov[3][qq][d2]) /
                  lsum[qq];
    float num = 0.f, den = 1e-6f;
#pragma unroll
    for (int dd = 0; dd < 64; ++dd) {
      float sqv = sq_s[qq][dd];
      num += sqv * Mg[(size_t)h * 4096 + dd * 64 + d2];
      den += sqv * zg[h * 64 + dd];
    }
    float gate = 1.f / (1.f + __expf(-ga[0]));
    float cv = gate * local + (1.f - gate) * num / den;
    comb[(size_t)(q0 + qq) * 1024 + h * 64 + d2] = (__bf16)cv;
  }
}

// ---------------- fallback attention (round-4-proven, verbatim) ----------------
__global__ __launch_bounds__(256) void attn_simple_k(const __bf16* __restrict__ QKV,
                                                     const float* __restrict__ amask,
                                                     const __bf16* __restrict__ rel16,
                                                     const float* __restrict__ Mg,
                                                     const float* __restrict__ zg,
                                                     const float* __restrict__ ga,
                                                     __bf16* __restrict__ comb) {
  const int q = blockIdx.x, h = blockIdx.y;
  const int tid = threadIdx.x;
  __shared__ float sc[1024];
  __shared__ float qs[64];
  __shared__ float red[256];
  __shared__ float ov[4][64];
  __shared__ float sq_s[64];

  if (tid < 64) qs[tid] = (float)QKV[(size_t)q * 3072 + h * 64 + tid];
  __syncthreads();

#pragma unroll
  for (int j = 0; j < 4; ++j) {
    int k = tid * 4 + j;
    const __bf16* kp = QKV + (size_t)k * 3072 + 1024 + h * 64;
    const __bf16* rp = rel16 + (size_t)(q - k + 1024) * 64;
    float s = 0.f;
#pragma unroll
    for (int c = 0; c < 8; ++c) {
      bf16x8 kv = *(const bf16x8*)(kp + c * 8);
      bf16x8 rv = *(const bf16x8*)(rp + c * 8);
#pragma unroll
      for (int e = 0; e < 8; ++e)
        s += (qs[c * 8 + e] + (float)rv[e]) * (float)kv[e];
    }
    sc[k] = s * 0.125f + amask[k] * (-1e9f);
  }
  __syncthreads();

  float m = -3.0e38f;
  for (int k = tid; k < 1024; k += 256) m = fmaxf(m, sc[k]);
  red[tid] = m;
  __syncthreads();
  for (int s = 128; s > 0; s >>= 1) {
    if (tid < s) red[tid] = fmaxf(red[tid], red[tid + s]);
    __syncthreads();
  }
  m = red[0];
  __syncthreads();

  float lp = 0.f;
  for (int k = tid; k < 1024; k += 256) {
    float e = __expf(sc[k] - m);
    sc[k] = e;
    lp += e;
  }
  red[tid] = lp;
  __syncthreads();
  for (int s = 128; s > 0; s >>= 1) {
    if (tid < s) red[tid] += red[tid + s];
    __syncthreads();
  }
  float lsum = red[0];

  const int d = tid & 63, w4 = tid >> 6;
  float o = 0.f;
  const __bf16* vbase = QKV + (size_t)(w4 * 256) * 3072 + 2048 + h * 64 + d;
  for (int k = 0; k < 256; ++k) o += sc[w4 * 256 + k] * (float)vbase[(size_t)k * 3072];
  ov[w4][d] = o;
  __syncthreads();

  if (tid < 64) {
    float x = qs[tid];
    sq_s[tid] = x > 0.f ? x + 1.f : __expf(x);
  }
  __syncthreads();
  if (tid < 64) {
    float local = (ov[0][tid] + ov[1][tid] + ov[2][tid] + ov[3][tid]) / lsum;
    float num = 0.f, den = 1e-6f;
    for (int dd = 0; dd < 64; ++dd) {
      num += sq_s[dd] * Mg[(size_t)h * 4096 + dd * 64 + tid];
      den += sq_s[dd] * zg[h * 64 + dd];
    }
    float gate = 1.f / (1.f + __expf(-ga[0]));
    float cv = gate * local + (1.f - gate) * num / den;
    comb[(size_t)q * 1024 + h * 64 + tid] = (__bf16)cv;
  }
}

// ---------------- launcher ----------------
extern "C" void kernel_launch(void* const* d_in, const int* in_sizes, int n_in,
                              void* d_out, int out_size, void* d_ws, size_t ws_size,
                              hipStream_t stream) {
  const int expect[14] = {4194304, 4096, 1048576, 1024, 1048576, 1024, 1048576,
                          1024, 1048576, 1024, 131136, 65536, 1024, 1};
  if (n_in != 14) return;
  for (int i = 0; i < 14; ++i)
    if (in_sizes[i] != expect[i]) return;

  char* ws = (char*)d_ws;
  int*    flag  = (int*)ws;                      // 4B
  float*  am32  = (float*)(ws + 1024);           // [4096]
  float*  b32   = (float*)(ws + 17408);          // bq|bk|bv|bo  [4][1024]
  float*  zg32  = (float*)(ws + 33792);          // [1024]
  float*  ga32  = (float*)(ws + 37888);          // [1]
  float*  Mg32  = (float*)(ws + 38912);          // [65536]
  __bf16* rel16 = (__bf16*)(ws + 301056);        // [131136]
  __bf16* hs16  = (__bf16*)(ws + 565248);        // [4096][1024]
  __bf16* W16   = (__bf16*)(ws + 8953856);       // 4x [1024][1024] (q,k,v,o)
  __bf16* qkv_b = (__bf16*)(ws + 17342464);      // [1024][3072]
  __bf16* comb  = (__bf16*)(ws + 23633920);      // [4096][1024]  ends 32022528
  __bf16* Vt    = (__bf16*)(ws + 32022528);      // [16][64][1024] ends 34119680

  const bool useVt = (ws_size >= 34119680);      // R12/R14/R15/R16-proven true

  detect_k<<<1, 256, 0, stream>>>((const uint32_t*)d_in[0], flag);

  cvt_to_bf16_k<<<16384, 256, 0, stream>>>(d_in[0], hs16, 4194304, flag);
  cvt_to_f32_k<<<16, 256, 0, stream>>>(d_in[1], am32, 4096, flag);
  const int widx[4] = {2, 4, 6, 8};
  for (int j = 0; j < 4; ++j) {
    cvt_to_bf16_k<<<4096, 256, 0, stream>>>(d_in[widx[j]], W16 + (size_t)j * 1048576,
                                            1048576, flag);
    cvt_to_f32_k<<<4, 256, 0, stream>>>(d_in[widx[j] + 1], b32 + j * 1024, 1024, flag);
  }
  cvt_to_bf16_k<<<513, 256, 0, stream>>>(d_in[10], rel16, 131136, flag);
  cvt_to_f32_k<<<256, 256, 0, stream>>>(d_in[11], Mg32, 65536, flag);
  cvt_to_f32_k<<<4, 256, 0, stream>>>(d_in[12], zg32, 1024, flag);
  cvt_to_f32_k<<<1, 256, 0, stream>>>(d_in[13], ga32, 1, flag);

  for (int b = 0; b < 4; ++b) {
    sgemm64_k<<<dim3(16, 16, 3), dim3(16, 16), 0, stream>>>(
        hs16 + (size_t)b * 1048576, W16, b32, qkv_b, 1024, 1024, 1024, 3072, 0);
    if (useVt) {
      vt_k<<<dim3(16, 16), 256, 0, stream>>>(qkv_b, Vt);
      attn_v9_k<<<dim3(256, 16), 256, 0, stream>>>(
          qkv_b, Vt, am32 + b * 1024, rel16, Mg32, zg32, ga32,
          comb + (size_t)b * 1048576);
    } else {
      attn_simple_k<<<dim3(1024, 16), 256, 0, stream>>>(
          qkv_b, am32 + b * 1024, rel16, Mg32, zg32, ga32, comb + (size_t)b * 1048576);
    }
  }

  sgemm64_out_k<<<dim3(64, 16), dim3(16, 16), 0, stream>>>(
      comb, W16 + 3 * 1048576, b32 + 3 * 1024, d_out, 4096, 1024, 1024, flag);
}